// Round 1
// baseline (193.517 us; speedup 1.0000x reference)
//
#include <hip/hip_runtime.h>

// MHA decode-style: B=1024, Nq=1, Nk=512, E=256, H=8, dh=32, fp32.
// One block (4 waves) per batch. Memory-bound: stream K+V (1 GB) once.

constexpr int NB = 1024;
constexpr int NK = 512;
constexpr int E  = 256;
constexpr int H  = 8;
constexpr int PAD_NK = NK + 4;   // (4h+k)%32 -> 8 distinct banks for stride-512 reads

__global__ __launch_bounds__(256, 4)
void mha_kernel(const float* __restrict__ q,
                const float* __restrict__ kmat,
                const float* __restrict__ vmat,
                const int* __restrict__ mask,
                const int* __restrict__ clip_p,
                float* __restrict__ out_attn,   // [B, E]
                float* __restrict__ out_prob)   // [B, NK]
{
    __shared__ float  s_sc[H][PAD_NK];   // ~16.1 KB scores -> probs
    __shared__ float4 s_part[4][64];     // 4 KB cross-wave PV reduce
    __shared__ int    s_mask[NK];        // 2 KB

    const int b    = blockIdx.x;
    const int tid  = threadIdx.x;
    const int lane = tid & 63;
    const int wave = tid >> 6;      // 0..3
    const int h    = lane >> 3;     // head owned by this lane's 8-lane group

    const float clipf = (float)(*clip_p);
    const float scale = 0.17677669529663687f;  // 1/sqrt(32)

    for (int i = tid; i < NK; i += 256) s_mask[i] = mask[(size_t)b * NK + i];

    // each lane's Q fragment: elements 4*lane .. 4*lane+3 (same for all waves)
    const float4 qf = *reinterpret_cast<const float4*>(q + (size_t)b * E + lane * 4);
    const float* kb = kmat + (size_t)b * NK * E;
    const float* vb = vmat + (size_t)b * NK * E;

    __syncthreads();

    // ---- Phase 1: scores = clip * tanh(mask ? -1e9 : qk/sqrt(dh)) ----
    for (int k0 = wave * 128; k0 < wave * 128 + 128; k0 += 4) {
        float4 kf[4];
        #pragma unroll
        for (int u = 0; u < 4; ++u)
            kf[u] = *reinterpret_cast<const float4*>(kb + (size_t)(k0 + u) * E + lane * 4);
        #pragma unroll
        for (int u = 0; u < 4; ++u) {
            float s = kf[u].x * qf.x + kf[u].y * qf.y + kf[u].z * qf.z + kf[u].w * qf.w;
            // sum across the 8 lanes of this head's segment (32 elems = 8 lanes x 4)
            s += __shfl_xor(s, 1);
            s += __shfl_xor(s, 2);
            s += __shfl_xor(s, 4);
            const int kk = k0 + u;
            float sc = s * scale;
            if (s_mask[kk] == 1) sc = -1e9f;
            // tanh via exp2-based expf; clamp so expf never overflows.
            sc = fminf(fmaxf(sc, -20.f), 20.f);
            const float ex = __expf(2.f * sc);
            const float th = (ex - 1.f) / (ex + 1.f);
            if ((lane & 7) == 0) s_sc[h][kk] = clipf * th;
        }
    }
    __syncthreads();

    // ---- Phase 2: per-head softmax over 512 keys (2 heads per wave) ----
    #pragma unroll
    for (int j = 0; j < 2; ++j) {
        const int hh = wave * 2 + j;
        float m = -1e30f;
        for (int k = lane; k < NK; k += 64) m = fmaxf(m, s_sc[hh][k]);
        #pragma unroll
        for (int off = 32; off; off >>= 1) m = fmaxf(m, __shfl_xor(m, off));
        float sum = 0.f;
        for (int k = lane; k < NK; k += 64) {
            const float e = __expf(s_sc[hh][k] - m);
            s_sc[hh][k] = e;
            sum += e;
        }
        #pragma unroll
        for (int off = 32; off; off >>= 1) sum += __shfl_xor(sum, off);
        const float inv = 1.0f / sum;
        for (int k = lane; k < NK; k += 64) s_sc[hh][k] *= inv;
    }
    __syncthreads();

    // ---- attn_prob_mean: mean over heads ----
    for (int k = tid; k < NK; k += 256) {
        float s = 0.f;
        #pragma unroll
        for (int hh = 0; hh < H; ++hh) s += s_sc[hh][k];
        out_prob[(size_t)b * NK + k] = s * 0.125f;
    }

    // ---- Phase 3: attn = P @ V ----
    float a0 = 0.f, a1 = 0.f, a2 = 0.f, a3 = 0.f;
    for (int k0 = wave * 128; k0 < wave * 128 + 128; k0 += 4) {
        float4 vf[4];
        #pragma unroll
        for (int u = 0; u < 4; ++u)
            vf[u] = *reinterpret_cast<const float4*>(vb + (size_t)(k0 + u) * E + lane * 4);
        #pragma unroll
        for (int u = 0; u < 4; ++u) {
            const float p = s_sc[h][k0 + u];   // padded stride -> conflict-free broadcast
            a0 += p * vf[u].x; a1 += p * vf[u].y; a2 += p * vf[u].z; a3 += p * vf[u].w;
        }
    }
    s_part[wave][lane] = make_float4(a0, a1, a2, a3);
    __syncthreads();
    if (tid < 64) {
        const float4 r0 = s_part[0][tid], r1 = s_part[1][tid],
                     r2 = s_part[2][tid], r3 = s_part[3][tid];
        float4 o;
        o.x = r0.x + r1.x + r2.x + r3.x;
        o.y = r0.y + r1.y + r2.y + r3.y;
        o.z = r0.z + r1.z + r2.z + r3.z;
        o.w = r0.w + r1.w + r2.w + r3.w;
        *reinterpret_cast<float4*>(out_attn + (size_t)b * E + tid * 4) = o;
    }
}

extern "C" void kernel_launch(void* const* d_in, const int* in_sizes, int n_in,
                              void* d_out, int out_size, void* d_ws, size_t ws_size,
                              hipStream_t stream) {
    const float* q    = (const float*)d_in[0];
    const float* kmat = (const float*)d_in[1];
    const float* vmat = (const float*)d_in[2];
    const int*   mask = (const int*)d_in[3];
    const int*   clip = (const int*)d_in[4];

    float* out_attn = (float*)d_out;                       // 1024*256 floats
    float* out_prob = (float*)d_out + (size_t)NB * E;      // 1024*512 floats

    mha_kernel<<<dim3(NB), dim3(256), 0, stream>>>(q, kmat, vmat, mask, clip,
                                                   out_attn, out_prob);
}